// Round 3
// baseline (150.725 us; speedup 1.0000x reference)
//
#include <hip/hip_runtime.h>

// Shapes: B=1, N=4096, C=256, H=8, d=32.
// ws layout (ushort elems):
//   Q[2][8][4096][32]          @ 0         (Q pre-scaled by d^-0.5*log2e)
//   K[2][8][4096][32]          @ KOFF
//   Vb[2][8][128][2][512]      @ VOFF      (V in PV B-frag LINEAR order:
//                                           per 32-key block kb, per 16-d tile,
//                                           elem (d_lo, slot) at
//                                           ((slot>>3)*16+d_lo)*8 + (slot&7))
//   WBF[24][8192]              @ WOFF      (W bf16, swizzled to B-frag order)

typedef __attribute__((ext_vector_type(8))) short short8;
typedef __attribute__((ext_vector_type(4))) float float4v;
typedef __attribute__((ext_vector_type(4))) unsigned int uint4v;

#define NTOK 4096
#define CDIM 256
#define HEADS 8
#define DHEAD 32

#define QOFF 0
#define KOFF (2*HEADS*NTOK*DHEAD)
#define VOFF (2*(2*HEADS*NTOK*DHEAD))
#define WOFF (3*(2*HEADS*NTOK*DHEAD))

__device__ inline unsigned short f2bf(float f) {
    union { float f; unsigned u; } v; v.f = f;
    unsigned r = v.u + 0x7FFFu + ((v.u >> 16) & 1u);   // RNE
    return (unsigned short)(r >> 16);
}

// exp2 + truncation-pack two S tiles (8 floats) into one PV A-fragment
__device__ inline short8 exp_pack(float4v S0, float4v S1) {
    union { float f; unsigned u; } u0,u1,u2,u3,u4,u5,u6,u7;
    u0.f = __builtin_amdgcn_exp2f(S0[0]);
    u1.f = __builtin_amdgcn_exp2f(S0[1]);
    u2.f = __builtin_amdgcn_exp2f(S0[2]);
    u3.f = __builtin_amdgcn_exp2f(S0[3]);
    u4.f = __builtin_amdgcn_exp2f(S1[0]);
    u5.f = __builtin_amdgcn_exp2f(S1[1]);
    u6.f = __builtin_amdgcn_exp2f(S1[2]);
    u7.f = __builtin_amdgcn_exp2f(S1[3]);
    union { short8 s8; uint4v u4v; } p;
    p.u4v[0] = __builtin_amdgcn_perm(u1.u, u0.u, 0x07060302u);
    p.u4v[1] = __builtin_amdgcn_perm(u3.u, u2.u, 0x07060302u);
    p.u4v[2] = __builtin_amdgcn_perm(u5.u, u4.u, 0x07060302u);
    p.u4v[3] = __builtin_amdgcn_perm(u7.u, u6.u, 0x07060302u);
    return p.s8;
}

// ---------------------------------------------------------------------------
// Kernel 0: W fp32 -> bf16, swizzled so a B-fragment is one contiguous 16B
// load: WBF[o32*8192 + (kk*2+nhalf)*512 + (quad*16+l16)*8 + j]
// ---------------------------------------------------------------------------
__global__ __launch_bounds__(256) void wconv_kernel(
    const float* __restrict__ W, unsigned short* __restrict__ ws)
{
    int idx = blockIdx.x*256 + threadIdx.x;    // [0, 24576): (row, col-octet)
    int R = idx >> 5, oct = idx & 31;
    int C = oct * 8;
    const float4* p = reinterpret_cast<const float4*>(W + R*CDIM + C);
    float4 a = p[0], b = p[1];
    short8 f;
    f[0]=(short)f2bf(a.x); f[1]=(short)f2bf(a.y); f[2]=(short)f2bf(a.z); f[3]=(short)f2bf(a.w);
    f[4]=(short)f2bf(b.x); f[5]=(short)f2bf(b.y); f[6]=(short)f2bf(b.z); f[7]=(short)f2bf(b.w);
    int o32 = R >> 5, r = R & 31;
    int kk = C >> 5, quad = (C >> 3) & 3;
    int dst = o32*8192 + (kk*2 + (r>>4))*512 + (quad*16 + (r&15))*8;
    *reinterpret_cast<short8*>(ws + WOFF + dst) = f;
}

// ---------------------------------------------------------------------------
// Kernel 1: t = x @ W^T (bf16 MFMA) + LayerNorm over d=32 groups.
// No LDS/barriers. grid = 1024: (row-tile 0..127) x (o-eighth 0..7, 3 o32s).
// ---------------------------------------------------------------------------
__global__ __launch_bounds__(256) void qkv_ln_kernel(
    const float* __restrict__ before, const float* __restrict__ after,
    const float* __restrict__ gamma, const float* __restrict__ beta,
    unsigned short* __restrict__ ws)
{
    const int tid  = threadIdx.x;
    const int lane = tid & 63;
    const int w    = tid >> 6;
    const int quad = lane >> 4;
    const int l16  = lane & 15;
    const int rt   = blockIdx.x >> 3;
    const int oq   = blockIdx.x & 7;

    const int mrow_frag = rt*64 + w*16 + l16;
    const int inp_f = mrow_frag >> 12;
    const int n_f   = mrow_frag & 4095;
    const float* x = inp_f ? after : before;

    short8 afrag[8];
#pragma unroll
    for (int kk = 0; kk < 8; kk++) {
        const float4* p = reinterpret_cast<const float4*>(x + n_f*CDIM + kk*32 + quad*8);
        float4 a = p[0], b = p[1];
        short8 f;
        f[0]=(short)f2bf(a.x); f[1]=(short)f2bf(a.y); f[2]=(short)f2bf(a.z); f[3]=(short)f2bf(a.w);
        f[4]=(short)f2bf(b.x); f[5]=(short)f2bf(b.y); f[6]=(short)f2bf(b.z); f[7]=(short)f2bf(b.w);
        afrag[kk] = f;
    }

    const float g0  = gamma[l16], g1  = gamma[16+l16];
    const float be0 = beta[l16],  be1 = beta[16+l16];
    const float cscale = 0.17677669529663687f * 1.4426950408889634f; // d^-0.5*log2e

    const int mrow_out  = rt*64 + w*16 + quad*4;
    const int inp_o     = mrow_out >> 12;
    const int n_o_base  = mrow_out & 4095;

    const unsigned short* wbf = ws + WOFF;

    for (int o32 = oq*3; o32 < oq*3 + 3; o32++) {
        const unsigned short* wb = wbf + o32*8192 + lane*8;
        float4v acc0 = {0.f,0.f,0.f,0.f}, acc1 = {0.f,0.f,0.f,0.f};
#pragma unroll
        for (int kk = 0; kk < 8; kk++) {
            short8 b0 = *reinterpret_cast<const short8*>(wb + (kk*2    )*512);
            short8 b1 = *reinterpret_cast<const short8*>(wb + (kk*2 + 1)*512);
            acc0 = __builtin_amdgcn_mfma_f32_16x16x32_bf16(afrag[kk], b0, acc0, 0,0,0);
            acc1 = __builtin_amdgcn_mfma_f32_16x16x32_bf16(afrag[kk], b1, acc1, 0,0,0);
        }

        const int which = o32 >> 3;     // 0=q 1=k 2=v
        const int h     = o32 & 7;
        unsigned short* qk = ws + (which == 0 ? QOFF : KOFF) + ((inp_o*HEADS + h)*NTOK)*DHEAD;
        unsigned short* vb = ws + VOFF + ((inp_o*HEADS + h)*128)*1024;
        const float qs = (which == 0) ? cscale : 1.0f;

#pragma unroll
        for (int i = 0; i < 4; i++) {
            float sum = acc0[i] + acc1[i];
            float sq  = acc0[i]*acc0[i] + acc1[i]*acc1[i];
#pragma unroll
            for (int m = 1; m < 16; m <<= 1) {
                sum += __shfl_xor(sum, m);
                sq  += __shfl_xor(sq,  m);
            }
            float mu   = sum * (1.0f/32.0f);
            float var  = sq * (1.0f/32.0f) - mu*mu;
            float rstd = rsqrtf(var + 1e-5f);
            float v0 = ((acc0[i]-mu)*rstd*g0 + be0) * qs;
            float v1 = ((acc1[i]-mu)*rstd*g1 + be1) * qs;
            int n = n_o_base + i;
            if (which < 2) {
                qk[n*DHEAD + l16]      = f2bf(v0);
                qk[n*DHEAD + 16 + l16] = f2bf(v1);
            } else {
                // B-frag linear layout: key n -> block kb, slot within block;
                // elem (d_lo, slot) at ((slot>>3)*16 + d_lo)*8 + (slot&7)
                int kb = n >> 5, ki = n & 31;
                int slot = ((ki & 15) >> 2)*8 + (ki & 3) + ((ki >> 4) << 2);
                int off  = ((slot >> 3)*16 + l16)*8 + (slot & 7);
                vb[kb*1024 + off]       = f2bf(v0);   // d = l16   (tile 0)
                vb[kb*1024 + 512 + off] = f2bf(v1);   // d = 16+l16 (tile 1)
            }
        }
    }
}

// ---------------------------------------------------------------------------
// Kernel 2: cross attention.
// R18 restructure (occupancy via smaller waves): block = 8 waves (512 thr)
//   = 4 key-quarters (kh) x 2 q-groups (qg). Each wave: 32 q-rows (qi=2),
//   1024 keys. Per-wave register state drops from ~108 (qi=4: 48 acc + 32
//   frag) to ~70 -> ~7 waves/SIMD instead of 4: the three ~20 µs pipe
//   demands (matrix / trans+VALU / L2) previously ran near-additively
//   because 4 same-phase waves couldn't cover each other's exp and L2
//   stalls (R16/R17 showed intra-wave reordering can't fix it).
// L2 traffic stays ~532 MB: the two qg-waves of each key-quarter stream
//   the SAME K/V lines from within one block -> L1 absorbs the 2x
//   duplication (pairwise temporal locality).
// Merge: kh=1..3 publish O/L per qg to LDS; kh=0 merges + writes.
// grid 1024 flat, XCD-pinned (h,X). Loop body = R15 (compiler-scheduled).
// ---------------------------------------------------------------------------
__global__ __launch_bounds__(512, 7) void attn_kernel(
    const unsigned short* __restrict__ ws, float* __restrict__ out)
{
    __shared__ float comb[2][3][32][34];        // [qg][kh-1][row][d0..31, l, pad]

    // XCD-locality decode: xcd = b&7 -> combo = xcd*2 + (i>>6), qb = i&63
    const int b    = blockIdx.x;
    const int xcd  = b & 7;
    const int i_   = b >> 3;                    // 0..127
    const int combo = xcd*2 + (i_ >> 6);        // 0..15
    const int h  = combo & 7;
    const int X  = combo >> 3;
    const int qb = i_ & 63;                     // 64 q-rows per block

    const int qinp = 1 - X, kvinp = X;
    const int tid  = threadIdx.x;
    const int lane = tid & 63;
    const int w    = tid >> 6;                  // 0..7
    const int qg   = w & 1;                     // q-group (32 rows)
    const int kh   = w >> 1;                    // key-quarter 0..3
    const int quad = lane >> 4;
    const int l16  = lane & 15;

    const unsigned short* qbase = ws + QOFF + ((qinp*HEADS + h)*NTOK)*DHEAD;
    const unsigned short* kbase = ws + KOFF + ((kvinp*HEADS + h)*NTOK)*DHEAD;
    const unsigned short* vbase = ws + VOFF + ((kvinp*HEADS + h)*128)*1024;

    const int q0 = qb*64 + qg*32;
    // Q as B-operand: B[n=q=l16][k=d=quad*8+j] — 2 fragments cover 32 q
    short8 qf[2];
#pragma unroll
    for (int qi = 0; qi < 2; qi++)
        qf[qi] = *reinterpret_cast<const short8*>(qbase + (q0 + qi*16 + l16)*DHEAD + quad*8);

    // K as A-operand (coalesced 1KB); V as B-operand (B-frag-linear, 1KB/blk)
    const unsigned short* kp = kbase + (kh*1024 + l16)*DHEAD + quad*8;
    const unsigned short* vp = vbase + (kh*32)*1024 + lane*8;

    const short8 ones = {0x3F80,0x3F80,0x3F80,0x3F80,0x3F80,0x3F80,0x3F80,0x3F80};

    float4v O[2][2], L[2];
#pragma unroll
    for (int qi = 0; qi < 2; qi++) {
        O[qi][0] = (float4v){0,0,0,0};
        O[qi][1] = (float4v){0,0,0,0};
        L[qi]    = (float4v){0,0,0,0};
    }
    const float4v z = {0,0,0,0};

    for (int t = 0; t < 32; t++) {              // 32-key steps over the quarter
        short8 kf0 = *reinterpret_cast<const short8*>(kp + (t*32     )*DHEAD);
        short8 kf1 = *reinterpret_cast<const short8*>(kp + (t*32 + 16)*DHEAD);
        short8 v0  = *reinterpret_cast<const short8*>(vp + t*1024);
        short8 v1  = *reinterpret_cast<const short8*>(vp + t*1024 + 512);
#pragma unroll
        for (int qi = 0; qi < 2; qi++) {        // 2 independent chains
            float4v S0 = __builtin_amdgcn_mfma_f32_16x16x32_bf16(kf0, qf[qi], z, 0,0,0);
            float4v S1 = __builtin_amdgcn_mfma_f32_16x16x32_bf16(kf1, qf[qi], z, 0,0,0);
            short8 pf = exp_pack(S0, S1);
            O[qi][0] = __builtin_amdgcn_mfma_f32_16x16x32_bf16(pf, v0,   O[qi][0], 0,0,0);
            O[qi][1] = __builtin_amdgcn_mfma_f32_16x16x32_bf16(pf, v1,   O[qi][1], 0,0,0);
            L[qi]    = __builtin_amdgcn_mfma_f32_16x16x32_bf16(pf, ones, L[qi],    0,0,0);
        }
    }

    // merge the 4 key-quarters per q-group: kh=1..3 publish, kh=0 merges.
    // O C-layout: row(q) = qi*16 + quad*4 + i, col(d) = l16 / 16+l16.
    if (kh > 0) {
#pragma unroll
        for (int qi = 0; qi < 2; qi++)
#pragma unroll
            for (int i = 0; i < 4; i++) {
                int row = qi*16 + quad*4 + i;
                comb[qg][kh-1][row][l16]      = O[qi][0][i];
                comb[qg][kh-1][row][16 + l16] = O[qi][1][i];
                if (l16 == 0) comb[qg][kh-1][row][32] = L[qi][i];
            }
    }
    __syncthreads();

    if (kh == 0) {
        float* ob = out + (size_t)X*NTOK*CDIM + h*DHEAD;
#pragma unroll
        for (int qi = 0; qi < 2; qi++) {
#pragma unroll
            for (int i = 0; i < 4; i++) {
                int row = qi*16 + quad*4 + i;
                float l  = L[qi][i]    + comb[qg][0][row][32]     + comb[qg][1][row][32]     + comb[qg][2][row][32];
                float a  = O[qi][0][i] + comb[qg][0][row][l16]    + comb[qg][1][row][l16]    + comb[qg][2][row][l16];
                float bb = O[qi][1][i] + comb[qg][0][row][16+l16] + comb[qg][1][row][16+l16] + comb[qg][2][row][16+l16];
                float inv = 1.0f / l;
                int orow = q0 + row;
                ob[orow*CDIM + l16]      = a  * inv;
                ob[orow*CDIM + 16 + l16] = bb * inv;
            }
        }
    }
}

extern "C" void kernel_launch(void* const* d_in, const int* in_sizes, int n_in,
                              void* d_out, int out_size, void* d_ws, size_t ws_size,
                              hipStream_t stream)
{
    const float* before = (const float*)d_in[0];
    const float* after  = (const float*)d_in[1];
    const float* W      = (const float*)d_in[2];
    const float* gamma  = (const float*)d_in[3];
    const float* beta   = (const float*)d_in[4];
    float* out          = (float*)d_out;
    unsigned short* ws  = (unsigned short*)d_ws;   // needs ~13.0 MB

    hipLaunchKernelGGL(wconv_kernel, dim3(96), dim3(256), 0, stream, W, ws);
    hipLaunchKernelGGL(qkv_ln_kernel, dim3(1024), dim3(256), 0, stream,
                       before, after, gamma, beta, ws);
    hipLaunchKernelGGL(attn_kernel, dim3(1024), dim3(512), 0, stream, ws, out);
}

// Round 4
// 141.746 us; speedup vs baseline: 1.0633x; 1.0633x over previous
//
#include <hip/hip_runtime.h>

// Shapes: B=1, N=4096, C=256, H=8, d=32.
// ws layout (ushort elems):
//   Q[2][8][4096][32]          @ 0         (Q pre-scaled by d^-0.5*log2e)
//   K[2][8][4096][32]          @ KOFF
//   Vb[2][8][128][2][512]      @ VOFF      (V in 32x32x16 PV B-frag LINEAR
//                                           order: per 32-key block kb, per
//                                           16-key tile kt, elem (key,d) at
//                                           kt*512 + (key>>3)*256 + d*8 + (key&7))
//   WBF[24][8192]              @ WOFF      (W bf16, swizzled to B-frag order)

typedef __attribute__((ext_vector_type(8))) short short8;
typedef __attribute__((ext_vector_type(4))) float float4v;
typedef __attribute__((ext_vector_type(16))) float f32x16;
typedef __attribute__((ext_vector_type(4))) unsigned int uint4v;

#define NTOK 4096
#define CDIM 256
#define HEADS 8
#define DHEAD 32

#define QOFF 0
#define KOFF (2*HEADS*NTOK*DHEAD)
#define VOFF (2*(2*HEADS*NTOK*DHEAD))
#define WOFF (3*(2*HEADS*NTOK*DHEAD))

__device__ inline unsigned short f2bf(float f) {
    union { float f; unsigned u; } v; v.f = f;
    unsigned r = v.u + 0x7FFFu + ((v.u >> 16) & 1u);   // RNE
    return (unsigned short)(r >> 16);
}

// pack two f32 -> one u32 of 2 bf16 (RNE), elem0 = lo16
__device__ inline unsigned cvt_pk_bf16(float lo, float hi) {
    unsigned r;
    asm("v_cvt_pk_bf16_f32 %0, %1, %2" : "=v"(r) : "v"(lo), "v"(hi));
    return r;
}
// swap a[32:63] <-> b[0:31]: a' = {a.lo, b.lo(moved up)}, b' = {a.hi(moved down), b.hi}
__device__ inline void plane32_swap(unsigned &a, unsigned &b) {
    asm("v_permlane32_swap_b32 %0, %1" : "+v"(a), "+v"(b));
}

// ---------------------------------------------------------------------------
// Kernel 0: W fp32 -> bf16, swizzled so a B-fragment is one contiguous 16B
// load: WBF[o32*8192 + (kk*2+nhalf)*512 + (quad*16+l16)*8 + j]
// ---------------------------------------------------------------------------
__global__ __launch_bounds__(256) void wconv_kernel(
    const float* __restrict__ W, unsigned short* __restrict__ ws)
{
    int idx = blockIdx.x*256 + threadIdx.x;    // [0, 24576): (row, col-octet)
    int R = idx >> 5, oct = idx & 31;
    int C = oct * 8;
    const float4* p = reinterpret_cast<const float4*>(W + R*CDIM + C);
    float4 a = p[0], b = p[1];
    short8 f;
    f[0]=(short)f2bf(a.x); f[1]=(short)f2bf(a.y); f[2]=(short)f2bf(a.z); f[3]=(short)f2bf(a.w);
    f[4]=(short)f2bf(b.x); f[5]=(short)f2bf(b.y); f[6]=(short)f2bf(b.z); f[7]=(short)f2bf(b.w);
    int o32 = R >> 5, r = R & 31;
    int kk = C >> 5, quad = (C >> 3) & 3;
    int dst = o32*8192 + (kk*2 + (r>>4))*512 + (quad*16 + (r&15))*8;
    *reinterpret_cast<short8*>(ws + WOFF + dst) = f;
}

// ---------------------------------------------------------------------------
// Kernel 1: t = x @ W^T (bf16 MFMA) + LayerNorm over d=32 groups.
// No LDS/barriers. grid = 1024: (row-tile 0..127) x (o-eighth 0..7, 3 o32s).
// R19: V-writer emits the 32x32x16 PV B-frag linear layout (see header).
// ---------------------------------------------------------------------------
__global__ __launch_bounds__(256) void qkv_ln_kernel(
    const float* __restrict__ before, const float* __restrict__ after,
    const float* __restrict__ gamma, const float* __restrict__ beta,
    unsigned short* __restrict__ ws)
{
    const int tid  = threadIdx.x;
    const int lane = tid & 63;
    const int w    = tid >> 6;
    const int quad = lane >> 4;
    const int l16  = lane & 15;
    const int rt   = blockIdx.x >> 3;
    const int oq   = blockIdx.x & 7;

    const int mrow_frag = rt*64 + w*16 + l16;
    const int inp_f = mrow_frag >> 12;
    const int n_f   = mrow_frag & 4095;
    const float* x = inp_f ? after : before;

    short8 afrag[8];
#pragma unroll
    for (int kk = 0; kk < 8; kk++) {
        const float4* p = reinterpret_cast<const float4*>(x + n_f*CDIM + kk*32 + quad*8);
        float4 a = p[0], b = p[1];
        short8 f;
        f[0]=(short)f2bf(a.x); f[1]=(short)f2bf(a.y); f[2]=(short)f2bf(a.z); f[3]=(short)f2bf(a.w);
        f[4]=(short)f2bf(b.x); f[5]=(short)f2bf(b.y); f[6]=(short)f2bf(b.z); f[7]=(short)f2bf(b.w);
        afrag[kk] = f;
    }

    const float g0  = gamma[l16], g1  = gamma[16+l16];
    const float be0 = beta[l16],  be1 = beta[16+l16];
    const float cscale = 0.17677669529663687f * 1.4426950408889634f; // d^-0.5*log2e

    const int mrow_out  = rt*64 + w*16 + quad*4;
    const int inp_o     = mrow_out >> 12;
    const int n_o_base  = mrow_out & 4095;

    const unsigned short* wbf = ws + WOFF;

    for (int o32 = oq*3; o32 < oq*3 + 3; o32++) {
        const unsigned short* wb = wbf + o32*8192 + lane*8;
        float4v acc0 = {0.f,0.f,0.f,0.f}, acc1 = {0.f,0.f,0.f,0.f};
#pragma unroll
        for (int kk = 0; kk < 8; kk++) {
            short8 b0 = *reinterpret_cast<const short8*>(wb + (kk*2    )*512);
            short8 b1 = *reinterpret_cast<const short8*>(wb + (kk*2 + 1)*512);
            acc0 = __builtin_amdgcn_mfma_f32_16x16x32_bf16(afrag[kk], b0, acc0, 0,0,0);
            acc1 = __builtin_amdgcn_mfma_f32_16x16x32_bf16(afrag[kk], b1, acc1, 0,0,0);
        }

        const int which = o32 >> 3;     // 0=q 1=k 2=v
        const int h     = o32 & 7;
        unsigned short* qk = ws + (which == 0 ? QOFF : KOFF) + ((inp_o*HEADS + h)*NTOK)*DHEAD;
        unsigned short* vb = ws + VOFF + ((inp_o*HEADS + h)*128)*1024;
        const float qs = (which == 0) ? cscale : 1.0f;

#pragma unroll
        for (int i = 0; i < 4; i++) {
            float sum = acc0[i] + acc1[i];
            float sq  = acc0[i]*acc0[i] + acc1[i]*acc1[i];
#pragma unroll
            for (int m = 1; m < 16; m <<= 1) {
                sum += __shfl_xor(sum, m);
                sq  += __shfl_xor(sq,  m);
            }
            float mu   = sum * (1.0f/32.0f);
            float var  = sq * (1.0f/32.0f) - mu*mu;
            float rstd = rsqrtf(var + 1e-5f);
            float v0 = ((acc0[i]-mu)*rstd*g0 + be0) * qs;
            float v1 = ((acc1[i]-mu)*rstd*g1 + be1) * qs;
            int n = n_o_base + i;
            if (which < 2) {
                qk[n*DHEAD + l16]      = f2bf(v0);
                qk[n*DHEAD + 16 + l16] = f2bf(v1);
            } else {
                // 32x32x16 B-frag linear layout: key n -> block kb (32),
                // ktile kt (16), elem (key,d) at kt*512+(kk>>3)*256+d*8+(kk&7)
                int kb = n >> 5, kt = (n >> 4) & 1, kk = n & 15;
                int base = kb*1024 + kt*512 + (kk>>3)*256 + (kk&7);
                vb[base + l16*8]      = f2bf(v0);   // d = l16
                vb[base + (16+l16)*8] = f2bf(v1);   // d = 16+l16
            }
        }
    }
}

// ---------------------------------------------------------------------------
// Kernel 2: cross attention — R15 wave structure (4 waves = 4 key-quarters,
// each wave: 64 q x 1024 keys), R19 compute restructure: 32x32x16 MFMA.
// Per 32-key step: 8 MFMA (4 S + 4 PV) x 32.3 cy vs previous 20 x 19.4 cy
// (-33% matrix-pipe demand, -60% MFMA issue slots); l accumulated via
// in-lane VALU adds (ones-MFMA removed). S^T C-layout gives each lane one
// q-column (l&31) and 16 keys; exp2 -> v_cvt_pk_bf16_f32 pairs -> 4
// v_permlane32_swap_b32 assemble both PV A-fragments in-register (each swap
// yields the j0/j2 (j1/j3) reg pair for the complementary lane halves).
// Loads stay at use sites (R16/R17 lesson: compiler schedules them best).
// grid 1024 flat, XCD-pinned (h,X).
// ---------------------------------------------------------------------------
__global__ __launch_bounds__(256, 4) void attn_kernel(
    const unsigned short* __restrict__ ws, float* __restrict__ out)
{
    __shared__ float comb[3][64][33];           // waves 1..3: [row][d0..31, l]
    __shared__ float l0s[64];                   // wave 0's l per row

    // XCD-locality decode: xcd = b&7 -> combo = xcd*2 + (i>>6), qb = i&63
    const int b    = blockIdx.x;
    const int xcd  = b & 7;
    const int i_   = b >> 3;                    // 0..127
    const int combo = xcd*2 + (i_ >> 6);        // 0..15
    const int h  = combo & 7;
    const int X  = combo >> 3;
    const int qb = i_ & 63;                     // 64 q-rows per block

    const int qinp = 1 - X, kvinp = X;
    const int tid  = threadIdx.x;
    const int lane = tid & 63;
    const int w    = tid >> 6;                  // key-quarter 0..3
    const int l31  = lane & 31;
    const int h5   = lane >> 5;

    const unsigned short* qbase = ws + QOFF + ((qinp*HEADS + h)*NTOK)*DHEAD;
    const unsigned short* kbase = ws + KOFF + ((kvinp*HEADS + h)*NTOK)*DHEAD;
    const unsigned short* vbase = ws + VOFF + ((kvinp*HEADS + h)*128)*1024;

    const int q0 = qb*64;
    // Q as B-operand (32x32x16): lane holds col q=l31, k = d = h5*8+j (+16*hf)
    short8 qf[2][2];
#pragma unroll
    for (int qt = 0; qt < 2; qt++)
#pragma unroll
        for (int hf = 0; hf < 2; hf++)
            qf[qt][hf] = *reinterpret_cast<const short8*>(
                qbase + (q0 + qt*32 + l31)*DHEAD + h5*8 + hf*16);

    // K as A-operand (32x32x16): lane holds row key=l31, k = d = h5*8+j (+16)
    const unsigned short* kp = kbase + (w*1024 + l31)*DHEAD + h5*8;
    // V as B-operand (32x32x16 linear layout): lane reads 16B at lane*8
    const unsigned short* vp = vbase + (w*32)*1024 + lane*8;

    f32x16 O0, O1;
#pragma unroll
    for (int r = 0; r < 16; r++) { O0[r] = 0.f; O1[r] = 0.f; }
    float Lp0 = 0.f, Lp1 = 0.f;
    f32x16 z16;
#pragma unroll
    for (int r = 0; r < 16; r++) z16[r] = 0.f;

    #define QT_STEP(QFA, QFB, O, LP)                                                        \
        do {                                                                                \
            f32x16 S = __builtin_amdgcn_mfma_f32_32x32x16_bf16(ka,  QFA, z16, 0,0,0);       \
            S = __builtin_amdgcn_mfma_f32_32x32x16_bf16(kb2, QFB, S, 0,0,0);                \
            float e0  = __builtin_amdgcn_exp2f(S[0]),  e1  = __builtin_amdgcn_exp2f(S[1]);  \
            float e2  = __builtin_amdgcn_exp2f(S[2]),  e3  = __builtin_amdgcn_exp2f(S[3]);  \
            float e4  = __builtin_amdgcn_exp2f(S[4]),  e5  = __builtin_amdgcn_exp2f(S[5]);  \
            float e6  = __builtin_amdgcn_exp2f(S[6]),  e7  = __builtin_amdgcn_exp2f(S[7]);  \
            float e8  = __builtin_amdgcn_exp2f(S[8]),  e9  = __builtin_amdgcn_exp2f(S[9]);  \
            float e10 = __builtin_amdgcn_exp2f(S[10]), e11 = __builtin_amdgcn_exp2f(S[11]); \
            float e12 = __builtin_amdgcn_exp2f(S[12]), e13 = __builtin_amdgcn_exp2f(S[13]); \
            float e14 = __builtin_amdgcn_exp2f(S[14]), e15 = __builtin_amdgcn_exp2f(S[15]); \
            LP += (((e0+e1)+(e2+e3))+((e4+e5)+(e6+e7)))                                     \
                + (((e8+e9)+(e10+e11))+((e12+e13)+(e14+e15)));                              \
            unsigned p0 = cvt_pk_bf16(e0,e1),   p1 = cvt_pk_bf16(e2,e3);                    \
            unsigned p2 = cvt_pk_bf16(e4,e5),   p3 = cvt_pk_bf16(e6,e7);                    \
            unsigned p4 = cvt_pk_bf16(e8,e9),   p5 = cvt_pk_bf16(e10,e11);                  \
            unsigned p6 = cvt_pk_bf16(e12,e13), p7 = cvt_pk_bf16(e14,e15);                  \
            plane32_swap(p0, p2); plane32_swap(p1, p3);                                     \
            plane32_swap(p4, p6); plane32_swap(p5, p7);                                     \
            union { unsigned u[4]; short8 s; } A1u, A2u;                                    \
            A1u.u[0]=p0; A1u.u[1]=p1; A1u.u[2]=p2; A1u.u[3]=p3;                             \
            A2u.u[0]=p4; A2u.u[1]=p5; A2u.u[2]=p6; A2u.u[3]=p7;                             \
            O = __builtin_amdgcn_mfma_f32_32x32x16_bf16(A1u.s, va,  O, 0,0,0);              \
            O = __builtin_amdgcn_mfma_f32_32x32x16_bf16(A2u.s, vb2, O, 0,0,0);              \
        } while (0)

    for (int t = 0; t < 32; t++) {              // 32-key steps over the quarter
        short8 ka  = *reinterpret_cast<const short8*>(kp + t*1024);        // d 0-15
        short8 kb2 = *reinterpret_cast<const short8*>(kp + t*1024 + 16);   // d 16-31
        short8 va  = *reinterpret_cast<const short8*>(vp + t*1024);        // keys 0-15
        short8 vb2 = *reinterpret_cast<const short8*>(vp + t*1024 + 512);  // keys 16-31
        QT_STEP(qf[0][0], qf[0][1], O0, Lp0);
        QT_STEP(qf[1][0], qf[1][1], O1, Lp1);
    }
    #undef QT_STEP

    // l: in-lane partial covers this lane-half's 16 keys/step; other half
    // has the complementary keys for the SAME q (q = l31 in both halves).
    float lsum0 = Lp0 + __shfl_xor(Lp0, 32);
    float lsum1 = Lp1 + __shfl_xor(Lp1, 32);

    // merge the 4 key-quarters: waves 1..3 publish, wave 0 merges + writes.
    // O C-layout (32x32): col d = l31, row q = (r&3)+8*(r>>2)+4*h5 (+32 for O1).
    if (w > 0) {
#pragma unroll
        for (int r = 0; r < 16; r++) {
            int row0 = (r&3) + 8*(r>>2) + 4*h5;
            comb[w-1][row0][l31]      = O0[r];
            comb[w-1][32 + row0][l31] = O1[r];
        }
        if (lane < 32) {
            comb[w-1][l31][32]      = lsum0;
            comb[w-1][32 + l31][32] = lsum1;
        }
    } else {
        if (lane < 32) { l0s[l31] = lsum0; l0s[32 + l31] = lsum1; }
    }
    __syncthreads();

    if (w == 0) {
        float* ob = out + (size_t)X*NTOK*CDIM + h*DHEAD;
#pragma unroll
        for (int r = 0; r < 16; r++) {
            int row0 = (r&3) + 8*(r>>2) + 4*h5;
            {
                int row = row0;
                float a = O0[r] + comb[0][row][l31] + comb[1][row][l31] + comb[2][row][l31];
                float l = l0s[row] + comb[0][row][32] + comb[1][row][32] + comb[2][row][32];
                ob[(size_t)(q0+row)*CDIM + l31] = a / l;
            }
            {
                int row = 32 + row0;
                float a = O1[r] + comb[0][row][l31] + comb[1][row][l31] + comb[2][row][l31];
                float l = l0s[row] + comb[0][row][32] + comb[1][row][32] + comb[2][row][32];
                ob[(size_t)(q0+row)*CDIM + l31] = a / l;
            }
        }
    }
}

extern "C" void kernel_launch(void* const* d_in, const int* in_sizes, int n_in,
                              void* d_out, int out_size, void* d_ws, size_t ws_size,
                              hipStream_t stream)
{
    const float* before = (const float*)d_in[0];
    const float* after  = (const float*)d_in[1];
    const float* W      = (const float*)d_in[2];
    const float* gamma  = (const float*)d_in[3];
    const float* beta   = (const float*)d_in[4];
    float* out          = (float*)d_out;
    unsigned short* ws  = (unsigned short*)d_ws;   // needs ~13.0 MB

    hipLaunchKernelGGL(wconv_kernel, dim3(96), dim3(256), 0, stream, W, ws);
    hipLaunchKernelGGL(qkv_ln_kernel, dim3(1024), dim3(256), 0, stream,
                       before, after, gamma, beta, ws);
    hipLaunchKernelGGL(attn_kernel, dim3(1024), dim3(256), 0, stream, ws, out);
}

// Round 6
// 135.638 us; speedup vs baseline: 1.1112x; 1.0450x over previous
//
#include <hip/hip_runtime.h>

// Shapes: B=1, N=4096, C=256, H=8, d=32.
// ws layout (ushort elems):
//   Q[2][8][4096][32]          @ 0         (Q pre-scaled by d^-0.5*log2e)
//   K[2][8][4096][32]          @ KOFF
//   Vb[2][8][128][2][512]      @ VOFF      (V in PV B-frag LINEAR order:
//                                           per 32-key block kb, per 16-d tile,
//                                           elem (d_lo, slot) at
//                                           ((slot>>3)*16+d_lo)*8 + (slot&7))
//   WBF[24][8192]              @ WOFF      (W bf16, swizzled to B-frag order)

typedef __attribute__((ext_vector_type(8))) short short8;
typedef __attribute__((ext_vector_type(4))) float float4v;
typedef __attribute__((ext_vector_type(4))) unsigned int uint4v;

#define NTOK 4096
#define CDIM 256
#define HEADS 8
#define DHEAD 32

#define QOFF 0
#define KOFF (2*HEADS*NTOK*DHEAD)
#define VOFF (2*(2*HEADS*NTOK*DHEAD))
#define WOFF (3*(2*HEADS*NTOK*DHEAD))

__device__ inline unsigned short f2bf(float f) {
    union { float f; unsigned u; } v; v.f = f;
    unsigned r = v.u + 0x7FFFu + ((v.u >> 16) & 1u);   // RNE
    return (unsigned short)(r >> 16);
}

// exp2 + truncation-pack two S tiles (8 floats) into one PV A-fragment
__device__ inline short8 exp_pack(float4v S0, float4v S1) {
    union { float f; unsigned u; } u0,u1,u2,u3,u4,u5,u6,u7;
    u0.f = __builtin_amdgcn_exp2f(S0[0]);
    u1.f = __builtin_amdgcn_exp2f(S0[1]);
    u2.f = __builtin_amdgcn_exp2f(S0[2]);
    u3.f = __builtin_amdgcn_exp2f(S0[3]);
    u4.f = __builtin_amdgcn_exp2f(S1[0]);
    u5.f = __builtin_amdgcn_exp2f(S1[1]);
    u6.f = __builtin_amdgcn_exp2f(S1[2]);
    u7.f = __builtin_amdgcn_exp2f(S1[3]);
    union { short8 s8; uint4v u4v; } p;
    p.u4v[0] = __builtin_amdgcn_perm(u1.u, u0.u, 0x07060302u);
    p.u4v[1] = __builtin_amdgcn_perm(u3.u, u2.u, 0x07060302u);
    p.u4v[2] = __builtin_amdgcn_perm(u5.u, u4.u, 0x07060302u);
    p.u4v[3] = __builtin_amdgcn_perm(u7.u, u6.u, 0x07060302u);
    return p.s8;
}

// async global->LDS DMA, 16 B per lane. LDS dest = wave-uniform base + lane*16.
// Global src is per-lane. Zero VGPR cost for in-flight data; counted by vmcnt.
__device__ inline void dma16(const unsigned short* g, unsigned short* l) {
    __builtin_amdgcn_global_load_lds(
        (const __attribute__((address_space(1))) void*)g,
        (__attribute__((address_space(3))) void*)l,
        16, 0, 0);
}

// ---------------------------------------------------------------------------
// Kernel 0: W fp32 -> bf16, swizzled so a B-fragment is one contiguous 16B
// load: WBF[o32*8192 + (kk*2+nhalf)*512 + (quad*16+l16)*8 + j]
// ---------------------------------------------------------------------------
__global__ __launch_bounds__(256) void wconv_kernel(
    const float* __restrict__ W, unsigned short* __restrict__ ws)
{
    int idx = blockIdx.x*256 + threadIdx.x;    // [0, 24576): (row, col-octet)
    int R = idx >> 5, oct = idx & 31;
    int C = oct * 8;
    const float4* p = reinterpret_cast<const float4*>(W + R*CDIM + C);
    float4 a = p[0], b = p[1];
    short8 f;
    f[0]=(short)f2bf(a.x); f[1]=(short)f2bf(a.y); f[2]=(short)f2bf(a.z); f[3]=(short)f2bf(a.w);
    f[4]=(short)f2bf(b.x); f[5]=(short)f2bf(b.y); f[6]=(short)f2bf(b.z); f[7]=(short)f2bf(b.w);
    int o32 = R >> 5, r = R & 31;
    int kk = C >> 5, quad = (C >> 3) & 3;
    int dst = o32*8192 + (kk*2 + (r>>4))*512 + (quad*16 + (r&15))*8;
    *reinterpret_cast<short8*>(ws + WOFF + dst) = f;
}

// ---------------------------------------------------------------------------
// Kernel 1: t = x @ W^T (bf16 MFMA) + LayerNorm over d=32 groups.
// No LDS/barriers. grid = 1024: (row-tile 0..127) x (o-eighth 0..7, 3 o32s).
// ---------------------------------------------------------------------------
__global__ __launch_bounds__(256) void qkv_ln_kernel(
    const float* __restrict__ before, const float* __restrict__ after,
    const float* __restrict__ gamma, const float* __restrict__ beta,
    unsigned short* __restrict__ ws)
{
    const int tid  = threadIdx.x;
    const int lane = tid & 63;
    const int w    = tid >> 6;
    const int quad = lane >> 4;
    const int l16  = lane & 15;
    const int rt   = blockIdx.x >> 3;
    const int oq   = blockIdx.x & 7;

    const int mrow_frag = rt*64 + w*16 + l16;
    const int inp_f = mrow_frag >> 12;
    const int n_f   = mrow_frag & 4095;
    const float* x = inp_f ? after : before;

    short8 afrag[8];
#pragma unroll
    for (int kk = 0; kk < 8; kk++) {
        const float4* p = reinterpret_cast<const float4*>(x + n_f*CDIM + kk*32 + quad*8);
        float4 a = p[0], b = p[1];
        short8 f;
        f[0]=(short)f2bf(a.x); f[1]=(short)f2bf(a.y); f[2]=(short)f2bf(a.z); f[3]=(short)f2bf(a.w);
        f[4]=(short)f2bf(b.x); f[5]=(short)f2bf(b.y); f[6]=(short)f2bf(b.z); f[7]=(short)f2bf(b.w);
        afrag[kk] = f;
    }

    const float g0  = gamma[l16], g1  = gamma[16+l16];
    const float be0 = beta[l16],  be1 = beta[16+l16];
    const float cscale = 0.17677669529663687f * 1.4426950408889634f; // d^-0.5*log2e

    const int mrow_out  = rt*64 + w*16 + quad*4;
    const int inp_o     = mrow_out >> 12;
    const int n_o_base  = mrow_out & 4095;

    const unsigned short* wbf = ws + WOFF;

    for (int o32 = oq*3; o32 < oq*3 + 3; o32++) {
        const unsigned short* wb = wbf + o32*8192 + lane*8;
        float4v acc0 = {0.f,0.f,0.f,0.f}, acc1 = {0.f,0.f,0.f,0.f};
#pragma unroll
        for (int kk = 0; kk < 8; kk++) {
            short8 b0 = *reinterpret_cast<const short8*>(wb + (kk*2    )*512);
            short8 b1 = *reinterpret_cast<const short8*>(wb + (kk*2 + 1)*512);
            acc0 = __builtin_amdgcn_mfma_f32_16x16x32_bf16(afrag[kk], b0, acc0, 0,0,0);
            acc1 = __builtin_amdgcn_mfma_f32_16x16x32_bf16(afrag[kk], b1, acc1, 0,0,0);
        }

        const int which = o32 >> 3;     // 0=q 1=k 2=v
        const int h     = o32 & 7;
        unsigned short* qk = ws + (which == 0 ? QOFF : KOFF) + ((inp_o*HEADS + h)*NTOK)*DHEAD;
        unsigned short* vb = ws + VOFF + ((inp_o*HEADS + h)*128)*1024;
        const float qs = (which == 0) ? cscale : 1.0f;

#pragma unroll
        for (int i = 0; i < 4; i++) {
            float sum = acc0[i] + acc1[i];
            float sq  = acc0[i]*acc0[i] + acc1[i]*acc1[i];
#pragma unroll
            for (int m = 1; m < 16; m <<= 1) {
                sum += __shfl_xor(sum, m);
                sq  += __shfl_xor(sq,  m);
            }
            float mu   = sum * (1.0f/32.0f);
            float var  = sq * (1.0f/32.0f) - mu*mu;
            float rstd = rsqrtf(var + 1e-5f);
            float v0 = ((acc0[i]-mu)*rstd*g0 + be0) * qs;
            float v1 = ((acc1[i]-mu)*rstd*g1 + be1) * qs;
            int n = n_o_base + i;
            if (which < 2) {
                qk[n*DHEAD + l16]      = f2bf(v0);
                qk[n*DHEAD + 16 + l16] = f2bf(v1);
            } else {
                // B-frag linear layout: key n -> block kb, slot within block;
                // elem (d_lo, slot) at ((slot>>3)*16 + d_lo)*8 + (slot&7)
                int kb = n >> 5, ki = n & 31;
                int slot = ((ki & 15) >> 2)*8 + (ki & 3) + ((ki >> 4) << 2);
                int off  = ((slot >> 3)*16 + l16)*8 + (slot & 7);
                vb[kb*1024 + off]       = f2bf(v0);   // d = l16   (tile 0)
                vb[kb*1024 + 512 + off] = f2bf(v1);   // d = 16+l16 (tile 1)
            }
        }
    }
}

// ---------------------------------------------------------------------------
// Kernel 2: cross attention — R15 structure (4 waves = 4 key-quarters, each
// wave all 64 q-rows), R20/R21: VGPR-FREE K/V PREFETCH via global_load_lds.
// Each wave DMAs step t+1's 4 KB (K0,K1,V0,V1; 16 B/lane, lane-order park
// buffer) into its private LDS double-buffer, waits a COUNTED vmcnt(4)
// (never 0 in-loop), then ds_reads step t. Registers hold no in-flight data
// so the compiler can't sink the prefetch (the R16 failure mode).
// R21 FIX: __syncthreads() BETWEEN loop exit and comb publish. comb aliases
// the kv DMA region; in R20 a fast wave's comb writes clobbered a slow
// wave's LIVE K/V buffers mid-loop (garbage -> exp2 inf -> inf/inf = NaN).
// At the barrier every wave has executed its own tail vmcnt(0) drain and
// consumed its last ds_reads, so the alias is dead from then on.
// LDS = 32 KB, 4 blocks/CU. grid 1024 flat, XCD-pinned (h,X).
// ---------------------------------------------------------------------------
__global__ __launch_bounds__(256, 4) void attn_kernel(
    const unsigned short* __restrict__ ws, float* __restrict__ out)
{
    // kv region: wave w, buffer b (2x): smem + w*4096 + b*2048 (ushorts)
    //   chunk offsets within buffer: K0 +0, K1 +512, V0 +1024, V1 +1536
    // comb merge buffer (float [3][64][33] = 25.3 KB) aliases the kv region;
    // only touched after the post-loop barrier (all DMA drained).
    __shared__ __align__(16) unsigned short smem[16384];   // 32 KB
    float (*comb)[64][33] = (float(*)[64][33])smem;

    // XCD-locality decode: xcd = b&7 -> combo = xcd*2 + (i>>6), qb = i&63
    const int b    = blockIdx.x;
    const int xcd  = b & 7;
    const int i_   = b >> 3;                    // 0..127
    const int combo = xcd*2 + (i_ >> 6);        // 0..15
    const int h  = combo & 7;
    const int X  = combo >> 3;
    const int qb = i_ & 63;                     // 64 q-rows per block

    const int qinp = 1 - X, kvinp = X;
    const int tid  = threadIdx.x;
    const int lane = tid & 63;
    const int w    = tid >> 6;                  // key-quarter 0..3
    const int quad = lane >> 4;
    const int l16  = lane & 15;

    const unsigned short* qbase = ws + QOFF + ((qinp*HEADS + h)*NTOK)*DHEAD;
    const unsigned short* kbase = ws + KOFF + ((kvinp*HEADS + h)*NTOK)*DHEAD;
    const unsigned short* vbase = ws + VOFF + ((kvinp*HEADS + h)*128)*1024;

    const int q0 = qb*64;
    // Q as B-operand: B[n=q=l16][k=d=quad*8+j] — 4 fragments cover 64 q
    short8 qf[4];
#pragma unroll
    for (int qi = 0; qi < 4; qi++)
        qf[qi] = *reinterpret_cast<const short8*>(qbase + (q0 + qi*16 + l16)*DHEAD + quad*8);

    // K as A-operand (coalesced 1KB); V as B-operand (B-frag-linear, 1KB/blk)
    const unsigned short* kp = kbase + (w*1024 + l16)*DHEAD + quad*8;
    const unsigned short* vp = vbase + (w*32)*1024 + lane*8;

    unsigned short* kv = smem + w*4096;         // this wave's 8 KB (2 buffers)

    const short8 ones = {0x3F80,0x3F80,0x3F80,0x3F80,0x3F80,0x3F80,0x3F80,0x3F80};

    float4v O[4][2], L[4];
#pragma unroll
    for (int qi = 0; qi < 4; qi++) {
        O[qi][0] = (float4v){0,0,0,0};
        O[qi][1] = (float4v){0,0,0,0};
        L[qi]    = (float4v){0,0,0,0};
    }
    const float4v z = {0,0,0,0};

    // prologue: DMA group for step 0 into buffer 0
    dma16(kp,        kv);
    dma16(kp + 512,  kv + 512);
    dma16(vp,        kv + 1024);
    dma16(vp + 512,  kv + 1536);

    for (int t = 0; t < 32; t++) {              // 32-key steps over the quarter
        unsigned short* cur = kv + (t & 1)*2048;
        if (t < 31) {
            // issue step t+1's DMA group into the other buffer (4 in flight)
            unsigned short* nxt = kv + ((t + 1) & 1)*2048;
            const unsigned short* kpt = kp + (t + 1)*1024;
            const unsigned short* vpt = vp + (t + 1)*1024;
            dma16(kpt,       nxt);
            dma16(kpt + 512, nxt + 512);
            dma16(vpt,       nxt + 1024);
            dma16(vpt + 512, nxt + 1536);
            // counted wait: allow the 4 just-issued to fly; step t's group done
            asm volatile("s_waitcnt vmcnt(4)" ::: "memory");
        } else {
            // tail: drain everything (alias handoff happens after the loop)
            asm volatile("s_waitcnt vmcnt(0)" ::: "memory");
        }

        short8 kf0 = *reinterpret_cast<const short8*>(cur + lane*8);
        short8 kf1 = *reinterpret_cast<const short8*>(cur + 512  + lane*8);
        short8 v0  = *reinterpret_cast<const short8*>(cur + 1024 + lane*8);
        short8 v1  = *reinterpret_cast<const short8*>(cur + 1536 + lane*8);
#pragma unroll
        for (int qi = 0; qi < 4; qi++) {        // 4 independent chains
            float4v S0 = __builtin_amdgcn_mfma_f32_16x16x32_bf16(kf0, qf[qi], z, 0,0,0);
            float4v S1 = __builtin_amdgcn_mfma_f32_16x16x32_bf16(kf1, qf[qi], z, 0,0,0);
            short8 pf = exp_pack(S0, S1);
            O[qi][0] = __builtin_amdgcn_mfma_f32_16x16x32_bf16(pf, v0,   O[qi][0], 0,0,0);
            O[qi][1] = __builtin_amdgcn_mfma_f32_16x16x32_bf16(pf, v1,   O[qi][1], 0,0,0);
            L[qi]    = __builtin_amdgcn_mfma_f32_16x16x32_bf16(pf, ones, L[qi],    0,0,0);
        }
    }

    // R21: rendezvous BEFORE the comb alias goes live — every wave has
    // drained its DMA queue (tail vmcnt(0)) and consumed its last ds_reads.
    __syncthreads();

    // merge the 4 key-quarters: waves 1..3 publish, wave 0 merges + writes.
    // L: row = q (quad*4+i within the qi tile), all cols equal.
    if (w > 0) {
#pragma unroll
        for (int qi = 0; qi < 4; qi++)
#pragma unroll
            for (int i = 0; i < 4; i++) {
                int row = qi*16 + quad*4 + i;
                comb[w-1][row][l16]      = O[qi][0][i];
                comb[w-1][row][16 + l16] = O[qi][1][i];
                if (l16 == 0) comb[w-1][row][32] = L[qi][i];
            }
    }
    __syncthreads();

    if (w == 0) {
        float* ob = out + (size_t)X*NTOK*CDIM + h*DHEAD;
#pragma unroll
        for (int qi = 0; qi < 4; qi++) {
#pragma unroll
            for (int i = 0; i < 4; i++) {
                int row = qi*16 + quad*4 + i;
                float l  = L[qi][i]    + comb[0][row][32]      + comb[1][row][32]      + comb[2][row][32];
                float a  = O[qi][0][i] + comb[0][row][l16]     + comb[1][row][l16]     + comb[2][row][l16];
                float bb = O[qi][1][i] + comb[0][row][16+l16]  + comb[1][row][16+l16]  + comb[2][row][16+l16];
                float inv = 1.0f / l;
                int orow = q0 + row;
                ob[orow*CDIM + l16]      = a  * inv;
                ob[orow*CDIM + 16 + l16] = bb * inv;
            }
        }
    }
}

extern "C" void kernel_launch(void* const* d_in, const int* in_sizes, int n_in,
                              void* d_out, int out_size, void* d_ws, size_t ws_size,
                              hipStream_t stream)
{
    const float* before = (const float*)d_in[0];
    const float* after  = (const float*)d_in[1];
    const float* W      = (const float*)d_in[2];
    const float* gamma  = (const float*)d_in[3];
    const float* beta   = (const float*)d_in[4];
    float* out          = (float*)d_out;
    unsigned short* ws  = (unsigned short*)d_ws;   // needs ~13.0 MB

    hipLaunchKernelGGL(wconv_kernel, dim3(96), dim3(256), 0, stream, W, ws);
    hipLaunchKernelGGL(qkv_ln_kernel, dim3(1024), dim3(256), 0, stream,
                       before, after, gamma, beta, ws);
    hipLaunchKernelGGL(attn_kernel, dim3(1024), dim3(256), 0, stream, ws, out);
}